// Round 1
// baseline (438.071 us; speedup 1.0000x reference)
//
#include <hip/hip_runtime.h>
#include <hip/hip_bf16.h>
#include <stdint.h>

// Conv 3x3 SAME, NHWC fp32 in/out, implicit GEMM via bf16 MFMA.
// M = B*H*W = 100352, N = COUT = 256, K = 9*256 = 2304.

#define IMG_B 32
#define IMG_H 56
#define IMG_W 56
#define CIN   256
#define COUT  256
#define KDIM  2304          // 3*3*256
#define M_TOT 100352

#define ASTR 40             // LDS row stride (bf16 elems) for A tile (32 data + 8 pad)
#define BSTR 40             // same for B tile

typedef __bf16 bf16_t;
typedef bf16_t bf16x8 __attribute__((ext_vector_type(8)));
typedef float  f32x4  __attribute__((ext_vector_type(4)));

// ---------- prep: HWIO f32 kernel[k][co] -> Wt bf16 [co][k] ----------
__global__ void prep_weights(const float* __restrict__ kern, bf16_t* __restrict__ wt) {
    int idx = blockIdx.x * 256 + threadIdx.x;          // 0 .. 2304*256-1
    int co  = idx / KDIM;
    int k   = idx - co * KDIM;
    wt[idx] = (bf16_t)kern[k * COUT + co];             // coalesced bf16 writes
}

// ---------- main conv: implicit GEMM, 128x128 tile, BK=32 ----------
__global__ __launch_bounds__(256)
void conv_mfma(const float* __restrict__ in, const bf16_t* __restrict__ wt,
               const float* __restrict__ bias, float* __restrict__ out)
{
    __shared__ bf16_t Al[128 * ASTR];   // A tile: 128 rows(m) x 32 k
    __shared__ bf16_t Bl[128 * BSTR];   // B tile: 128 rows(n=co) x 32 k

    const int tid   = threadIdx.x;
    const int ntile = blockIdx.x & 1;
    const int mtile = blockIdx.x >> 1;

    // ---- staging roles: 2 threads per tile row, 16 elems each ----
    const int arow = tid >> 1;
    const int aseg = tid & 1;              // which 16-elem half of the 32-k chunk
    const int m    = mtile * 128 + arow;
    const int bb   = m / (IMG_H * IMG_W);
    const int rem  = m - bb * (IMG_H * IMG_W);
    const int yy   = rem / IMG_W;
    const int xx   = rem - yy * IMG_W;

    const bf16_t* wt_row = wt + (size_t)(ntile * 128 + arow) * KDIM + aseg * 16;

    // ---- compute roles ----
    const int wave = tid >> 6;
    const int lane = tid & 63;
    const int wm   = wave & 1;             // 64-row quadrant
    const int wn   = wave >> 1;            // 64-col quadrant
    const int lrow = lane & 15;
    const int q    = lane >> 4;            // quad within wave

    f32x4 acc[4][4] = {};

    #pragma unroll 1
    for (int it = 0; it < 72; ++it) {
        // k0 = it*32 ; tap = it/8 gives (kh,kw), ci0 = (it%8)*32
        const int tap = it >> 3;
        const int kh  = tap / 3;
        const int kw  = tap - kh * 3;
        const int ci0 = (it & 7) << 5;

        const int iy = yy + kh - 1;
        const int ix = xx + kw - 1;
        const bool valid = ((unsigned)iy < IMG_H) && ((unsigned)ix < IMG_W);

        // global loads (before barrier so they overlap the previous compute's tail)
        f32x4 va[4] = {};
        if (valid) {
            const f32x4* src = (const f32x4*)(in +
                ((((size_t)bb * IMG_H + iy) * IMG_W + ix) * CIN + ci0 + aseg * 16));
            va[0] = src[0]; va[1] = src[1]; va[2] = src[2]; va[3] = src[3];
        }
        const uint4 wb0 = *(const uint4*)(wt_row + it * 32);       // 8 bf16
        const uint4 wb1 = *(const uint4*)(wt_row + it * 32 + 8);   // 8 bf16

        __syncthreads();   // previous iter's compute done before LDS overwrite

        // convert fp32 -> bf16, store A (2 x 16B) ; store B (2 x 16B)
        bf16x8 pa0, pa1;
        #pragma unroll
        for (int e = 0; e < 8; ++e) pa0[e] = (bf16_t)va[e >> 2][e & 3];
        #pragma unroll
        for (int e = 0; e < 8; ++e) pa1[e] = (bf16_t)va[2 + (e >> 2)][e & 3];
        *(bf16x8*)(&Al[arow * ASTR + aseg * 16])     = pa0;
        *(bf16x8*)(&Al[arow * ASTR + aseg * 16 + 8]) = pa1;
        *(uint4*)(&Bl[arow * BSTR + aseg * 16])      = wb0;
        *(uint4*)(&Bl[arow * BSTR + aseg * 16 + 8])  = wb1;

        __syncthreads();

        // fragment loads: 8 x ds_read_b128
        bf16x8 af[4], bf[4];
        #pragma unroll
        for (int i = 0; i < 4; ++i)
            af[i] = *(const bf16x8*)(&Al[(wm * 64 + i * 16 + lrow) * ASTR + q * 8]);
        #pragma unroll
        for (int j = 0; j < 4; ++j)
            bf[j] = *(const bf16x8*)(&Bl[(wn * 64 + j * 16 + lrow) * BSTR + q * 8]);

        #pragma unroll
        for (int i = 0; i < 4; ++i)
            #pragma unroll
            for (int j = 0; j < 4; ++j)
                acc[i][j] = __builtin_amdgcn_mfma_f32_16x16x32_bf16(af[i], bf[j], acc[i][j], 0, 0, 0);
    }

    // ---- epilogue: C/D layout col = lane&15, row = q*4 + reg ----
    const int co_base = ntile * 128 + wn * 64;
    float bv[4];
    #pragma unroll
    for (int j = 0; j < 4; ++j) bv[j] = bias[co_base + j * 16 + lrow];

    const int mrow_base = mtile * 128 + wm * 64;
    #pragma unroll
    for (int i = 0; i < 4; ++i) {
        #pragma unroll
        for (int rr = 0; rr < 4; ++rr) {
            const int mm = mrow_base + i * 16 + q * 4 + rr;
            float* op = out + (size_t)mm * COUT + co_base;
            #pragma unroll
            for (int j = 0; j < 4; ++j)
                op[j * 16 + lrow] = acc[i][j][rr] + bv[j];
        }
    }
}

extern "C" void kernel_launch(void* const* d_in, const int* in_sizes, int n_in,
                              void* d_out, int out_size, void* d_ws, size_t ws_size,
                              hipStream_t stream) {
    const float* inputs = (const float*)d_in[0];
    const float* kernel = (const float*)d_in[1];
    const float* bias   = (const float*)d_in[2];
    float*       outp   = (float*)d_out;
    bf16_t*      wt     = (bf16_t*)d_ws;          // needs 2304*256*2 = 1.18 MB

    // weight transpose+convert: 2304*256 elements, 256/block
    prep_weights<<<KDIM * COUT / 256, 256, 0, stream>>>(kernel, wt);

    // conv: 784 m-tiles x 2 n-tiles
    conv_mfma<<<(M_TOT / 128) * 2, 256, 0, stream>>>(inputs, wt, bias, outp);
}

// Round 3
// 363.504 us; speedup vs baseline: 1.2051x; 1.2051x over previous
//
#include <hip/hip_runtime.h>
#include <hip/hip_bf16.h>
#include <stdint.h>

// Conv 3x3 SAME, NHWC fp32 in/out, implicit GEMM via bf16 MFMA.
// M = B*H*W = 100352, N = COUT = 256, K = 9*256 = 2304.
// Round 3: zero-padded bf16 input image in ws -> conv staging is UNIFORM
// global_load_lds (no divergent DMA, no mixed ds_write zero-fill — the
// round-2 crash suspect). Structure otherwise identical to validated m97.

#define IMG_B 32
#define IMG_H 56
#define IMG_W 56
#define CIN   256
#define COUT  256
#define KDIM  2304          // 3*3*256
#define M_TOT 100352
#define HW    (IMG_H * IMG_W)
#define PW    58            // padded width
#define PHW   (PW * PW)     // 3364 padded pixels per image

typedef __bf16 bf16_t;
typedef bf16_t bf16x8 __attribute__((ext_vector_type(8)));
typedef float  f32x4  __attribute__((ext_vector_type(4)));

typedef const __attribute__((address_space(1))) void GV;
typedef __attribute__((address_space(3))) void LV;

__device__ __forceinline__ void async16(const bf16_t* g, bf16_t* l) {
    // LDS dest = wave-uniform(l) + laneid*16; 16B per lane
    __builtin_amdgcn_global_load_lds((GV*)g, (LV*)l, 16, 0, 0);
}

// ---------- prep: fp32 NHWC input -> zero-padded bf16 [B][58][58][C] ----------
__global__ void prep_pad(const float* __restrict__ in, bf16_t* __restrict__ out) {
    const size_t e = ((size_t)blockIdx.x * 256 + threadIdx.x) * 8;
    const int pix = (int)(e >> 8);          // padded pixel index
    const int c0  = (int)(e & 255);
    const int b   = pix / PHW;
    const int r   = pix - b * PHW;
    const int py  = r / PW;
    const int px  = r - py * PW;
    bf16x8 v = {};                          // border default: zeros
    if (py >= 1 && py <= IMG_H && px >= 1 && px <= IMG_W) {
        const f32x4* s = (const f32x4*)(in +
            ((((size_t)b * IMG_H + (py - 1)) * IMG_W + (px - 1)) << 8) + c0);
        f32x4 a = s[0], bq = s[1];
        #pragma unroll
        for (int k = 0; k < 4; ++k) v[k] = (bf16_t)a[k];
        #pragma unroll
        for (int k = 0; k < 4; ++k) v[4 + k] = (bf16_t)bq[k];
    }
    *(bf16x8*)(out + e) = v;
}

// ---------- prep: HWIO f32 kernel[k][co] -> Wt bf16 [co][k] ----------
__global__ void prep_weights(const float* __restrict__ kern, bf16_t* __restrict__ wt) {
    int idx = blockIdx.x * 256 + threadIdx.x;          // 0 .. 2304*256-1
    int co  = idx / KDIM;
    int k   = idx - co * KDIM;
    wt[idx] = (bf16_t)kern[k * COUT + co];             // coalesced bf16 writes
}

// ---------- main conv (padded bf16): 128x128 tile, BK=32, uniform DMA ----------
__global__ __launch_bounds__(256)
void conv_mfma_p(const bf16_t* __restrict__ P, const bf16_t* __restrict__ wt,
                 const float* __restrict__ bias, float* __restrict__ out)
{
    __shared__ bf16_t Al[128 * 32];   // unpadded — required by global_load_lds
    __shared__ bf16_t Bl[128 * 32];

    const int tid  = threadIdx.x;
    const int wave = tid >> 6;
    const int lane = tid & 63;

    // XCD-contiguous tile mapping: blocks on one XCD cover 98 contiguous m-tiles
    const int bid   = blockIdx.x;
    const int tile  = (bid & 7) * 196 + (bid >> 3);
    const int ntile = tile & 1;
    const int mtile = tile >> 1;

    // ---- staging roles: 4 lanes per row, 16B (8 bf16) per lane ----
    const int rloc = lane >> 2;       // row within this wave's 16-row group
    const int seg  = lane & 3;        // 16B segment within 64B row

    const bf16_t* abase[2];
    const bf16_t* wrow[2];
    bf16_t* alds[2];
    bf16_t* blds[2];
    #pragma unroll
    for (int j = 0; j < 2; ++j) {
        const int m   = mtile * 128 + j * 64 + wave * 16 + rloc;
        const int bb  = m / HW;
        const int rem = m - bb * HW;
        const int yy  = rem / IMG_W;
        const int xx  = rem - yy * IMG_W;
        // padded origin: tap (kh,kw) reads padded[yy+kh][xx+kw]
        abase[j] = P + (((size_t)bb * PHW + yy * PW + xx) << 8) + seg * 8;
        const int co = ntile * 128 + j * 64 + wave * 16 + rloc;
        wrow[j] = wt + (size_t)co * KDIM + seg * 8;
        alds[j] = &Al[(j * 64 + wave * 16) * 32];   // wave-uniform bases
        blds[j] = &Bl[(j * 64 + wave * 16) * 32];
    }

    // ---- compute roles ----
    const int wm   = wave & 1;
    const int wn   = wave >> 1;
    const int lrow = lane & 15;
    const int q    = lane >> 4;

    f32x4 acc[4][4] = {};

    #pragma unroll 1
    for (int it = 0; it < 72; ++it) {
        const int tap = it >> 3;
        const int kh  = tap / 3;
        const int kw  = tap - kh * 3;
        const int koff = ((kh * PW + kw) << 8) + ((it & 7) << 5);  // uniform scalar

        #pragma unroll
        for (int j = 0; j < 2; ++j) {
            async16(abase[j] + koff, alds[j]);
            async16(wrow[j] + it * 32, blds[j]);
        }

        __syncthreads();   // drains DMA vmcnt before fragment reads

        bf16x8 af[4], bf[4];
        #pragma unroll
        for (int i = 0; i < 4; ++i)
            af[i] = *(const bf16x8*)(&Al[(wm * 64 + i * 16 + lrow) * 32 + q * 8]);
        #pragma unroll
        for (int j = 0; j < 4; ++j)
            bf[j] = *(const bf16x8*)(&Bl[(wn * 64 + j * 16 + lrow) * 32 + q * 8]);

        #pragma unroll
        for (int i = 0; i < 4; ++i)
            #pragma unroll
            for (int j = 0; j < 4; ++j)
                acc[i][j] = __builtin_amdgcn_mfma_f32_16x16x32_bf16(af[i], bf[j], acc[i][j], 0, 0, 0);

        __syncthreads();   // compute done before next iter's staging overwrites
    }

    // ---- epilogue: C/D layout col = lane&15, row = q*4 + reg ----
    const int co_base = ntile * 128 + wn * 64;
    float bv[4];
    #pragma unroll
    for (int j = 0; j < 4; ++j) bv[j] = bias[co_base + j * 16 + lrow];

    const int mrow_base = mtile * 128 + wm * 64;
    #pragma unroll
    for (int i = 0; i < 4; ++i) {
        #pragma unroll
        for (int rr = 0; rr < 4; ++rr) {
            const int mm = mrow_base + i * 16 + q * 4 + rr;
            float* op = out + (size_t)mm * COUT + co_base;
            #pragma unroll
            for (int j = 0; j < 4; ++j)
                op[j * 16 + lrow] = acc[i][j][rr] + bv[j];
        }
    }
}

// ---------- fallback conv (fp32 staging, round-1 validated, 316 us) ----------
#define ASTR 40
#define BSTR 40
__global__ __launch_bounds__(256)
void conv_mfma(const float* __restrict__ in, const bf16_t* __restrict__ wt,
               const float* __restrict__ bias, float* __restrict__ out)
{
    __shared__ bf16_t Alf[128 * ASTR];
    __shared__ bf16_t Blf[128 * BSTR];

    const int tid   = threadIdx.x;
    const int ntile = blockIdx.x & 1;
    const int mtile = blockIdx.x >> 1;

    const int arow = tid >> 1;
    const int aseg = tid & 1;
    const int m    = mtile * 128 + arow;
    const int bb   = m / HW;
    const int rem  = m - bb * HW;
    const int yy   = rem / IMG_W;
    const int xx   = rem - yy * IMG_W;

    const bf16_t* wt_row = wt + (size_t)(ntile * 128 + arow) * KDIM + aseg * 16;

    const int wave = tid >> 6;
    const int lane = tid & 63;
    const int wm   = wave & 1;
    const int wn   = wave >> 1;
    const int lrow = lane & 15;
    const int q    = lane >> 4;

    f32x4 acc[4][4] = {};

    #pragma unroll 1
    for (int it = 0; it < 72; ++it) {
        const int tap = it >> 3;
        const int kh  = tap / 3;
        const int kw  = tap - kh * 3;
        const int ci0 = (it & 7) << 5;

        const int iy = yy + kh - 1;
        const int ix = xx + kw - 1;
        const bool valid = ((unsigned)iy < IMG_H) && ((unsigned)ix < IMG_W);

        f32x4 va[4] = {};
        if (valid) {
            const f32x4* src = (const f32x4*)(in +
                ((((size_t)bb * IMG_H + iy) * IMG_W + ix) * CIN + ci0 + aseg * 16));
            va[0] = src[0]; va[1] = src[1]; va[2] = src[2]; va[3] = src[3];
        }
        const uint4 wb0 = *(const uint4*)(wt_row + it * 32);
        const uint4 wb1 = *(const uint4*)(wt_row + it * 32 + 8);

        __syncthreads();

        bf16x8 pa0, pa1;
        #pragma unroll
        for (int e = 0; e < 8; ++e) pa0[e] = (bf16_t)va[e >> 2][e & 3];
        #pragma unroll
        for (int e = 0; e < 8; ++e) pa1[e] = (bf16_t)va[2 + (e >> 2)][e & 3];
        *(bf16x8*)(&Alf[arow * ASTR + aseg * 16])     = pa0;
        *(bf16x8*)(&Alf[arow * ASTR + aseg * 16 + 8]) = pa1;
        *(uint4*)(&Blf[arow * BSTR + aseg * 16])      = wb0;
        *(uint4*)(&Blf[arow * BSTR + aseg * 16 + 8])  = wb1;

        __syncthreads();

        bf16x8 af[4], bf[4];
        #pragma unroll
        for (int i = 0; i < 4; ++i)
            af[i] = *(const bf16x8*)(&Alf[(wm * 64 + i * 16 + lrow) * ASTR + q * 8]);
        #pragma unroll
        for (int j = 0; j < 4; ++j)
            bf[j] = *(const bf16x8*)(&Blf[(wn * 64 + j * 16 + lrow) * BSTR + q * 8]);

        #pragma unroll
        for (int i = 0; i < 4; ++i)
            #pragma unroll
            for (int j = 0; j < 4; ++j)
                acc[i][j] = __builtin_amdgcn_mfma_f32_16x16x32_bf16(af[i], bf[j], acc[i][j], 0, 0, 0);
    }

    const int co_base = ntile * 128 + wn * 64;
    float bv[4];
    #pragma unroll
    for (int j = 0; j < 4; ++j) bv[j] = bias[co_base + j * 16 + lrow];

    const int mrow_base = mtile * 128 + wm * 64;
    #pragma unroll
    for (int i = 0; i < 4; ++i) {
        #pragma unroll
        for (int rr = 0; rr < 4; ++rr) {
            const int mm = mrow_base + i * 16 + q * 4 + rr;
            float* op = out + (size_t)mm * COUT + co_base;
            #pragma unroll
            for (int j = 0; j < 4; ++j)
                op[j * 16 + lrow] = acc[i][j][rr] + bv[j];
        }
    }
}

extern "C" void kernel_launch(void* const* d_in, const int* in_sizes, int n_in,
                              void* d_out, int out_size, void* d_ws, size_t ws_size,
                              hipStream_t stream) {
    const float* inputs = (const float*)d_in[0];
    const float* kernel = (const float*)d_in[1];
    const float* bias   = (const float*)d_in[2];
    float*       outp   = (float*)d_out;

    const size_t p_elems = (size_t)IMG_B * PHW * CIN;               // 27,557,888
    const size_t p_bytes = p_elems * sizeof(bf16_t);                // 55.1 MB
    const size_t w_bytes = (size_t)KDIM * COUT * sizeof(bf16_t);    // 1.18 MB

    if (ws_size >= p_bytes + w_bytes) {
        bf16_t* pimg = (bf16_t*)d_ws;
        bf16_t* wt   = (bf16_t*)((char*)d_ws + p_bytes);
        prep_pad<<<(int)(p_elems / 8 / 256), 256, 0, stream>>>(inputs, pimg);
        prep_weights<<<KDIM * COUT / 256, 256, 0, stream>>>(kernel, wt);
        conv_mfma_p<<<(M_TOT / 128) * 2, 256, 0, stream>>>(pimg, wt, bias, outp);
    } else {
        bf16_t* wt = (bf16_t*)d_ws;
        prep_weights<<<KDIM * COUT / 256, 256, 0, stream>>>(kernel, wt);
        conv_mfma<<<(M_TOT / 128) * 2, 256, 0, stream>>>(inputs, wt, bias, outp);
    }
}

// Round 4
// 315.117 us; speedup vs baseline: 1.3902x; 1.1536x over previous
//
#include <hip/hip_runtime.h>
#include <hip/hip_bf16.h>
#include <stdint.h>

// Conv 3x3 SAME, NHWC fp32 in/out, implicit GEMM via bf16 MFMA.
// M = B*H*W = 100352, N = COUT = 256, K = 9*256 = 2304.
// Round 4: BK=64 + mfma_32x32x16 (half the barriers/issues), XOR-swizzled
// LDS via source-pointer permutation (conflict-free b128 reads), DMA for
// it+1 issued before MFMA of it (overlap DMA flight with MFMA pipe).

#define IMG_B 32
#define IMG_H 56
#define IMG_W 56
#define CIN   256
#define COUT  256
#define KDIM  2304          // 3*3*256
#define M_TOT 100352
#define HW    (IMG_H * IMG_W)
#define PW    58            // padded width
#define PHW   (PW * PW)     // 3364 padded pixels per image
#define BK    64            // k-elems per tile
#define ITERS (KDIM / BK)   // 36

typedef __bf16 bf16_t;
typedef bf16_t bf16x8 __attribute__((ext_vector_type(8)));
typedef float  f32x4  __attribute__((ext_vector_type(4)));
typedef float  f32x16 __attribute__((ext_vector_type(16)));

typedef const __attribute__((address_space(1))) void GV;
typedef __attribute__((address_space(3))) void LV;

__device__ __forceinline__ void async16(const bf16_t* g, bf16_t* l) {
    // LDS dest = wave-uniform(l) + laneid*16; 16B per lane
    __builtin_amdgcn_global_load_lds((GV*)g, (LV*)l, 16, 0, 0);
}

// ---------- prep: fp32 NHWC input -> zero-padded bf16 [B][58][58][C] ----------
__global__ void prep_pad(const float* __restrict__ in, bf16_t* __restrict__ out) {
    const size_t e = ((size_t)blockIdx.x * 256 + threadIdx.x) * 8;
    const int pix = (int)(e >> 8);          // padded pixel index
    const int c0  = (int)(e & 255);
    const int b   = pix / PHW;
    const int r   = pix - b * PHW;
    const int py  = r / PW;
    const int px  = r - py * PW;
    bf16x8 v = {};                          // border default: zeros
    if (py >= 1 && py <= IMG_H && px >= 1 && px <= IMG_W) {
        const f32x4* s = (const f32x4*)(in +
            ((((size_t)b * IMG_H + (py - 1)) * IMG_W + (px - 1)) << 8) + c0);
        f32x4 a = s[0], bq = s[1];
        #pragma unroll
        for (int k = 0; k < 4; ++k) v[k] = (bf16_t)a[k];
        #pragma unroll
        for (int k = 0; k < 4; ++k) v[4 + k] = (bf16_t)bq[k];
    }
    *(bf16x8*)(out + e) = v;
}

// ---------- prep: HWIO f32 kernel[k][co] -> Wt bf16 [co][k] ----------
__global__ void prep_weights(const float* __restrict__ kern, bf16_t* __restrict__ wt) {
    int idx = blockIdx.x * 256 + threadIdx.x;          // 0 .. 2304*256-1
    int co  = idx / KDIM;
    int k   = idx - co * KDIM;
    wt[idx] = (bf16_t)kern[k * COUT + co];             // coalesced bf16 writes
}

// ---------- main conv: 128x128 tile, BK=64, 32x32x16 MFMA, swizzled LDS ----------
__global__ __launch_bounds__(256)
void conv_mfma_p(const bf16_t* __restrict__ P, const bf16_t* __restrict__ wt,
                 const float* __restrict__ bias, float* __restrict__ out)
{
    __shared__ bf16_t Al[128 * BK];   // 16 KB, row-major [row][k], seg-swizzled
    __shared__ bf16_t Bl[128 * BK];   // 16 KB

    const int tid  = threadIdx.x;
    const int wave = tid >> 6;
    const int lane = tid & 63;

    // XCD-contiguous tile mapping: blocks on one XCD cover 98 contiguous m-tiles
    const int bid   = blockIdx.x;
    const int tile  = (bid & 7) * 196 + (bid >> 3);
    const int ntile = tile & 1;
    const int mtile = tile >> 1;

    // ---- staging roles: per DMA issue, 8 rows x 8 segs of 16B per wave ----
    const int rl = lane >> 3;         // row within 8-row group
    const int sl = lane & 7;          // LDS slot within row
    const int u  = sl ^ rl;           // swizzle: slot sl holds source seg u = sl^(row&7)

    const bf16_t* asrc[4];
    const bf16_t* bsrc[4];
    bf16_t* alds[4];
    bf16_t* blds[4];
    #pragma unroll
    for (int i = 0; i < 4; ++i) {
        const int row = wave * 32 + i * 8 + rl;     // tile row 0..127
        const int m   = mtile * 128 + row;
        const int bb  = m / HW;
        const int rem = m - bb * HW;
        const int yy  = rem / IMG_W;
        const int xx  = rem - yy * IMG_W;
        asrc[i] = P + (((size_t)bb * PHW + yy * PW + xx) << 8) + u * 8;
        const int co = ntile * 128 + row;
        bsrc[i] = wt + (size_t)co * KDIM + u * 8;
        alds[i] = &Al[(wave * 32 + i * 8) * BK];    // wave-uniform bases
        blds[i] = &Bl[(wave * 32 + i * 8) * BK];
    }

    // ---- compute roles: wave (wm,wn) owns 64x64; 2x2 of 32x32 MFMA tiles ----
    const int wm = wave & 1;
    const int wn = wave >> 1;
    const int ln = lane & 31;
    const int lh = lane >> 5;
    const int rx = ln & 7;            // row&7 for swizzled read

    f32x16 acc[2][2] = {};

    // prologue: stage iter 0 (tap 0 => koff 0)
    #pragma unroll
    for (int i = 0; i < 4; ++i) {
        async16(asrc[i], alds[i]);
        async16(bsrc[i], blds[i]);
    }

    #pragma unroll 1
    for (int it = 0; it < ITERS; ++it) {
        __syncthreads();   // DMA for iter `it` complete in LDS

        // fragment reads: 16 x ds_read_b128, conflict-free via swizzle
        bf16x8 af[2][4], bf[2][4];
        #pragma unroll
        for (int kk = 0; kk < 4; ++kk) {
            const int slot = ((kk * 2 + lh) ^ rx) * 8;
            #pragma unroll
            for (int g = 0; g < 2; ++g) {
                af[g][kk] = *(const bf16x8*)(&Al[(wm * 64 + g * 32 + ln) * BK + slot]);
                bf[g][kk] = *(const bf16x8*)(&Bl[(wn * 64 + g * 32 + ln) * BK + slot]);
            }
        }

        __syncthreads();   // reads done; LDS free for next iter's DMA

        if (it + 1 < ITERS) {      // issue next DMA BEFORE the MFMA block
            const int itn  = it + 1;
            const int tap  = itn >> 2;
            const int kh   = tap / 3;
            const int kw   = tap - kh * 3;
            const int koff = ((kh * PW + kw) << 8) + ((itn & 3) << 6);
            const int woff = itn * BK;
            #pragma unroll
            for (int i = 0; i < 4; ++i) {
                async16(asrc[i] + koff, alds[i]);
                async16(bsrc[i] + woff, blds[i]);
            }
        }

        // MFMA: 16 x 32x32x16 (DMA flight overlaps this)
        #pragma unroll
        for (int kk = 0; kk < 4; ++kk)
            #pragma unroll
            for (int g = 0; g < 2; ++g)
                #pragma unroll
                for (int h = 0; h < 2; ++h)
                    acc[g][h] = __builtin_amdgcn_mfma_f32_32x32x16_bf16(
                        af[g][kk], bf[h][kk], acc[g][h], 0, 0, 0);
    }

    // ---- epilogue: 32x32 C/D layout col=lane&31, row=(reg&3)+8*(reg>>2)+4*lh ----
    const int mbase  = mtile * 128 + wm * 64;
    const int cobase = ntile * 128 + wn * 64;
    float bv[2];
    #pragma unroll
    for (int h = 0; h < 2; ++h) bv[h] = bias[cobase + h * 32 + ln];

    #pragma unroll
    for (int g = 0; g < 2; ++g) {
        #pragma unroll
        for (int reg = 0; reg < 16; ++reg) {
            const int mm = mbase + g * 32 + (reg & 3) + 8 * (reg >> 2) + 4 * lh;
            float* op = out + (size_t)mm * COUT + cobase + ln;
            op[0]  = acc[g][0][reg] + bv[0];
            op[32] = acc[g][1][reg] + bv[1];
        }
    }
}

// ---------- fallback conv (fp32 staging, round-1 validated) ----------
#define ASTR 40
#define BSTR 40
__global__ __launch_bounds__(256)
void conv_mfma(const float* __restrict__ in, const bf16_t* __restrict__ wt,
               const float* __restrict__ bias, float* __restrict__ out)
{
    __shared__ bf16_t Alf[128 * ASTR];
    __shared__ bf16_t Blf[128 * BSTR];

    const int tid   = threadIdx.x;
    const int ntile = blockIdx.x & 1;
    const int mtile = blockIdx.x >> 1;

    const int arow = tid >> 1;
    const int aseg = tid & 1;
    const int m    = mtile * 128 + arow;
    const int bb   = m / HW;
    const int rem  = m - bb * HW;
    const int yy   = rem / IMG_W;
    const int xx   = rem - yy * IMG_W;

    const bf16_t* wt_row = wt + (size_t)(ntile * 128 + arow) * KDIM + aseg * 16;

    const int wave = tid >> 6;
    const int lane = tid & 63;
    const int wm   = wave & 1;
    const int wn   = wave >> 1;
    const int lrow = lane & 15;
    const int q    = lane >> 4;

    f32x4 acc[4][4] = {};

    #pragma unroll 1
    for (int it = 0; it < 72; ++it) {
        const int tap = it >> 3;
        const int kh  = tap / 3;
        const int kw  = tap - kh * 3;
        const int ci0 = (it & 7) << 5;

        const int iy = yy + kh - 1;
        const int ix = xx + kw - 1;
        const bool valid = ((unsigned)iy < IMG_H) && ((unsigned)ix < IMG_W);

        f32x4 va[4] = {};
        if (valid) {
            const f32x4* src = (const f32x4*)(in +
                ((((size_t)bb * IMG_H + iy) * IMG_W + ix) * CIN + ci0 + aseg * 16));
            va[0] = src[0]; va[1] = src[1]; va[2] = src[2]; va[3] = src[3];
        }
        const uint4 wb0 = *(const uint4*)(wt_row + it * 32);
        const uint4 wb1 = *(const uint4*)(wt_row + it * 32 + 8);

        __syncthreads();

        bf16x8 pa0, pa1;
        #pragma unroll
        for (int e = 0; e < 8; ++e) pa0[e] = (bf16_t)va[e >> 2][e & 3];
        #pragma unroll
        for (int e = 0; e < 8; ++e) pa1[e] = (bf16_t)va[2 + (e >> 2)][e & 3];
        *(bf16x8*)(&Alf[arow * ASTR + aseg * 16])     = pa0;
        *(bf16x8*)(&Alf[arow * ASTR + aseg * 16 + 8]) = pa1;
        *(uint4*)(&Blf[arow * BSTR + aseg * 16])      = wb0;
        *(uint4*)(&Blf[arow * BSTR + aseg * 16 + 8])  = wb1;

        __syncthreads();

        bf16x8 af[4], bf[4];
        #pragma unroll
        for (int i = 0; i < 4; ++i)
            af[i] = *(const bf16x8*)(&Alf[(wm * 64 + i * 16 + lrow) * ASTR + q * 8]);
        #pragma unroll
        for (int j = 0; j < 4; ++j)
            bf[j] = *(const bf16x8*)(&Blf[(wn * 64 + j * 16 + lrow) * BSTR + q * 8]);

        #pragma unroll
        for (int i = 0; i < 4; ++i)
            #pragma unroll
            for (int j = 0; j < 4; ++j)
                acc[i][j] = __builtin_amdgcn_mfma_f32_16x16x32_bf16(af[i], bf[j], acc[i][j], 0, 0, 0);
    }

    const int co_base = ntile * 128 + wn * 64;
    float bv[4];
    #pragma unroll
    for (int j = 0; j < 4; ++j) bv[j] = bias[co_base + j * 16 + lrow];

    const int mrow_base = mtile * 128 + wm * 64;
    #pragma unroll
    for (int i = 0; i < 4; ++i) {
        #pragma unroll
        for (int rr = 0; rr < 4; ++rr) {
            const int mm = mrow_base + i * 16 + q * 4 + rr;
            float* op = out + (size_t)mm * COUT + co_base;
            #pragma unroll
            for (int j = 0; j < 4; ++j)
                op[j * 16 + lrow] = acc[i][j][rr] + bv[j];
        }
    }
}

extern "C" void kernel_launch(void* const* d_in, const int* in_sizes, int n_in,
                              void* d_out, int out_size, void* d_ws, size_t ws_size,
                              hipStream_t stream) {
    const float* inputs = (const float*)d_in[0];
    const float* kernel = (const float*)d_in[1];
    const float* bias   = (const float*)d_in[2];
    float*       outp   = (float*)d_out;

    const size_t p_elems = (size_t)IMG_B * PHW * CIN;               // 27,557,888
    const size_t p_bytes = p_elems * sizeof(bf16_t);                // 55.1 MB
    const size_t w_bytes = (size_t)KDIM * COUT * sizeof(bf16_t);    // 1.18 MB

    if (ws_size >= p_bytes + w_bytes) {
        bf16_t* pimg = (bf16_t*)d_ws;
        bf16_t* wt   = (bf16_t*)((char*)d_ws + p_bytes);
        prep_pad<<<(int)(p_elems / 8 / 256), 256, 0, stream>>>(inputs, pimg);
        prep_weights<<<KDIM * COUT / 256, 256, 0, stream>>>(kernel, wt);
        conv_mfma_p<<<(M_TOT / 128) * 2, 256, 0, stream>>>(pimg, wt, bias, outp);
    } else {
        bf16_t* wt = (bf16_t*)d_ws;
        prep_weights<<<KDIM * COUT / 256, 256, 0, stream>>>(kernel, wt);
        conv_mfma<<<(M_TOT / 128) * 2, 256, 0, stream>>>(inputs, wt, bias, outp);
    }
}